// Round 1
// baseline (108.164 us; speedup 1.0000x reference)
//
#include <hip/hip_runtime.h>
#include <math.h>

#define Bc 4
#define Lc 48
#define Kc 32
#define Dc 128
#define ROWS (Bc*Lc*Kc)      // 6144
#define RT 24                // rows per GEMM tile
#define NRT (ROWS/RT)        // 256

static_assert(NRT == 256, "sel decode assumes 256 row tiles");

// ---------- Kernel A family: out = act(in @ W + bias), row-tiled ----------
// 256 threads; thread = 3 rows x 4 cols register tile; W fully staged in LDS.
__device__ __forceinline__ void tile_gemm_body(
    const float* __restrict__ in, const float* __restrict__ W,
    const float* __restrict__ bias, float* __restrict__ out,
    int r0, bool relu)
{
    __shared__ float sA[RT*Dc];      // 12 KB
    __shared__ float sB[Dc*Dc];      // 64 KB
    __shared__ float sBias[Dc];
    const int tid = threadIdx.x;

    {   // stage W (4096 float4, coalesced)
        const float4* src = (const float4*)W;
        float4* dst = (float4*)sB;
        #pragma unroll
        for (int i = 0; i < (Dc*Dc/4)/256; ++i) dst[tid + i*256] = src[tid + i*256];
    }
    {   // stage A rows (contiguous 24*128 floats)
        const float4* src = (const float4*)(in + r0*Dc);
        float4* dst = (float4*)sA;
        #pragma unroll
        for (int i = 0; i < (RT*Dc/4)/256; ++i) dst[tid + i*256] = src[tid + i*256];
    }
    if (tid < Dc/4) {
        float4 b4 = bias ? ((const float4*)bias)[tid] : make_float4(0.f,0.f,0.f,0.f);
        ((float4*)sBias)[tid] = b4;
    }
    __syncthreads();

    const int rg = tid >> 5;             // 0..7 -> rows rg*3..rg*3+2
    const int c0 = (tid & 31) * 4;       // cols c0..c0+3
    const float* A0 = sA + rg*3*Dc;
    float acc[3][4] = {};

    #pragma unroll 8
    for (int k = 0; k < Dc; k += 4) {
        float4 a0 = *(const float4*)(A0 + k);
        float4 a1 = *(const float4*)(A0 + Dc + k);
        float4 a2 = *(const float4*)(A0 + 2*Dc + k);
        float4 b0 = *(const float4*)(sB + (k+0)*Dc + c0);
        float4 b1 = *(const float4*)(sB + (k+1)*Dc + c0);
        float4 b2 = *(const float4*)(sB + (k+2)*Dc + c0);
        float4 b3 = *(const float4*)(sB + (k+3)*Dc + c0);
        float a_[3][4] = {{a0.x,a0.y,a0.z,a0.w},{a1.x,a1.y,a1.z,a1.w},{a2.x,a2.y,a2.z,a2.w}};
        float b_[4][4] = {{b0.x,b0.y,b0.z,b0.w},{b1.x,b1.y,b1.z,b1.w},
                          {b2.x,b2.y,b2.z,b2.w},{b3.x,b3.y,b3.z,b3.w}};
        #pragma unroll
        for (int r = 0; r < 3; ++r)
            #pragma unroll
            for (int c = 0; c < 4; ++c)
                #pragma unroll
                for (int q = 0; q < 4; ++q)
                    acc[r][c] = fmaf(a_[r][q], b_[q][c], acc[r][c]);
    }

    #pragma unroll
    for (int r = 0; r < 3; ++r) {
        float4 v;
        v.x = acc[r][0] + sBias[c0+0];
        v.y = acc[r][1] + sBias[c0+1];
        v.z = acc[r][2] + sBias[c0+2];
        v.w = acc[r][3] + sBias[c0+3];
        if (relu) {
            v.x = fmaxf(v.x, 0.f); v.y = fmaxf(v.y, 0.f);
            v.z = fmaxf(v.z, 0.f); v.w = fmaxf(v.w, 0.f);
        }
        *(float4*)(out + (r0 + rg*3 + r)*Dc + c0) = v;
    }
}

__global__ __launch_bounds__(256) void k_gemm_t(
    const float* __restrict__ h, const float* __restrict__ Wm1,
    const float* __restrict__ bm1, float* __restrict__ t_ws)
{
    tile_gemm_body(h, Wm1, bm1, t_ws, blockIdx.x * RT, true);
}

__global__ __launch_bounds__(256) void k_gemm_rest(
    const float* __restrict__ h, const float* __restrict__ t_ws,
    const float* __restrict__ Wm2, const float* __restrict__ bm2,
    const float* __restrict__ Wa1, const float* __restrict__ ba1,
    float* __restrict__ msg_ws, float* __restrict__ hip_ws,
    float* __restrict__ hjp_ws)
{
    const int sel = blockIdx.x >> 8;          // 0..2
    const int r0  = (blockIdx.x & 255) * RT;
    const float* in; const float* W; const float* bias; float* out;
    if (sel == 0)      { in = t_ws; W = Wm2;          bias = bm2;     out = msg_ws; }
    else if (sel == 1) { in = h;    W = Wa1;          bias = ba1;     out = hip_ws; } // ba1 folded here
    else               { in = h;    W = Wa1 + Dc*Dc;  bias = nullptr; out = hjp_ws; }
    tile_gemm_body(in, W, bias, out, r0, false);
}

// ---------- Kernel B: logits + softmax + aggregation + residual + LN ----------
// block = (b, k, i-half of 24 i's); 512 threads = 8 waves; wave owns 3 i's.
__global__ __launch_bounds__(512) void k_attn(
    const float* __restrict__ h,
    const float* __restrict__ hip_ws, const float* __restrict__ hjp_ws,
    const float* __restrict__ msg_ws,
    const float* __restrict__ wa2, const float* __restrict__ gamma,
    const float* __restrict__ beta, float* __restrict__ out)
{
    const int blk = blockIdx.x;
    const int b  = blk >> 6;          // 64 blocks per b
    const int k  = (blk >> 1) & 31;
    const int i0 = (blk & 1) * 24;

    __shared__ float HJ[48*132];      // hj_proj rows (ba1 NOT here; folded into hip)
    __shared__ float MS[48*132];      // messages rows
    __shared__ float HI[24*132];      // hi_proj(+ba1) rows for this i-half
    __shared__ float WA[Dc];
    __shared__ float GM[Dc];
    __shared__ float BT[Dc];
    __shared__ float WT[24*48];       // attention weights

    const int tid = threadIdx.x;

    for (int idx = tid; idx < 48*32; idx += 512) {
        const int j = idx >> 5, c4 = (idx & 31) * 4;
        const int g = ((b*Lc + j)*Kc + k)*Dc + c4;
        *(float4*)(HJ + j*132 + c4) = *(const float4*)(hjp_ws + g);
        *(float4*)(MS + j*132 + c4) = *(const float4*)(msg_ws + g);
    }
    for (int idx = tid; idx < 24*32; idx += 512) {
        const int i = idx >> 5, c4 = (idx & 31) * 4;
        const int g = ((b*Lc + i0 + i)*Kc + k)*Dc + c4;
        *(float4*)(HI + i*132 + c4) = *(const float4*)(hip_ws + g);
    }
    if (tid < 32)       ((float4*)WA)[tid]      = ((const float4*)wa2)[tid];
    else if (tid < 64)  ((float4*)GM)[tid - 32] = ((const float4*)gamma)[tid - 32];
    else if (tid < 96)  ((float4*)BT)[tid - 64] = ((const float4*)beta)[tid - 64];
    __syncthreads();

    const int wave = tid >> 6;
    const int lane = tid & 63;
    const int il0  = wave * 3;        // 8 waves * 3 = 24 local i's
    const bool jv  = lane < 48;
    const int  jl  = jv ? lane : 0;

    // ---- logits: lane = j, 3 i's register-tiled ----
    float s0 = 0.f, s1 = 0.f, s2 = 0.f;
    {
        const float* hj = HJ + jl*132;
        const float* hA = HI + il0*132;
        const float* hB = hA + 132;
        const float* hC = hB + 132;
        #pragma unroll 4
        for (int d = 0; d < Dc; d += 4) {
            const float4 hj4 = *(const float4*)(hj + d);
            const float4 w4  = *(const float4*)(WA + d);
            const float4 a4  = *(const float4*)(hA + d);
            const float4 b4  = *(const float4*)(hB + d);
            const float4 c4  = *(const float4*)(hC + d);
            s0 = fmaf(fmaxf(a4.x + hj4.x, 0.f), w4.x, s0);
            s0 = fmaf(fmaxf(a4.y + hj4.y, 0.f), w4.y, s0);
            s0 = fmaf(fmaxf(a4.z + hj4.z, 0.f), w4.z, s0);
            s0 = fmaf(fmaxf(a4.w + hj4.w, 0.f), w4.w, s0);
            s1 = fmaf(fmaxf(b4.x + hj4.x, 0.f), w4.x, s1);
            s1 = fmaf(fmaxf(b4.y + hj4.y, 0.f), w4.y, s1);
            s1 = fmaf(fmaxf(b4.z + hj4.z, 0.f), w4.z, s1);
            s1 = fmaf(fmaxf(b4.w + hj4.w, 0.f), w4.w, s1);
            s2 = fmaf(fmaxf(c4.x + hj4.x, 0.f), w4.x, s2);
            s2 = fmaf(fmaxf(c4.y + hj4.y, 0.f), w4.y, s2);
            s2 = fmaf(fmaxf(c4.z + hj4.z, 0.f), w4.z, s2);
            s2 = fmaf(fmaxf(c4.w + hj4.w, 0.f), w4.w, s2);
        }
    }

    // ---- softmax over j (48 active lanes); ba2 cancels (shift-invariant) ----
    float sv[3] = { jv ? s0 : -1e30f, jv ? s1 : -1e30f, jv ? s2 : -1e30f };
    #pragma unroll
    for (int q = 0; q < 3; ++q) {
        float m = sv[q];
        #pragma unroll
        for (int off = 32; off; off >>= 1) m = fmaxf(m, __shfl_xor(m, off));
        const float p = jv ? __expf(sv[q] - m) : 0.f;
        float sum = p;
        #pragma unroll
        for (int off = 32; off; off >>= 1) sum += __shfl_xor(sum, off);
        if (jv) WT[(il0 + q)*48 + lane] = p / sum;
    }
    __syncthreads();

    // ---- aggregation: lane = d-pair; then residual + LayerNorm ----
    const int d0 = lane * 2;
    float ac[3][2] = {};
    const float* wt0 = WT + il0*48;
    const float* wt1 = wt0 + 48;
    const float* wt2 = wt1 + 48;
    #pragma unroll 4
    for (int j = 0; j < 48; ++j) {
        const float2 m2 = *(const float2*)(MS + j*132 + d0);
        const float wA = wt0[j], wB = wt1[j], wC = wt2[j];
        ac[0][0] = fmaf(wA, m2.x, ac[0][0]); ac[0][1] = fmaf(wA, m2.y, ac[0][1]);
        ac[1][0] = fmaf(wB, m2.x, ac[1][0]); ac[1][1] = fmaf(wB, m2.y, ac[1][1]);
        ac[2][0] = fmaf(wC, m2.x, ac[2][0]); ac[2][1] = fmaf(wC, m2.y, ac[2][1]);
    }
    const float gm0 = GM[d0], gm1 = GM[d0+1], bt0 = BT[d0], bt1 = BT[d0+1];
    #pragma unroll
    for (int q = 0; q < 3; ++q) {
        const int i = i0 + il0 + q;
        const int g = ((b*Lc + i)*Kc + k)*Dc + d0;
        const float2 h2 = *(const float2*)(h + g);
        const float x0 = h2.x + ac[q][0];
        const float x1 = h2.y + ac[q][1];
        float ps = x0 + x1;
        float pq = x0*x0 + x1*x1;
        #pragma unroll
        for (int off = 32; off; off >>= 1) {
            ps += __shfl_xor(ps, off);
            pq += __shfl_xor(pq, off);
        }
        const float mu  = ps * (1.f/128.f);
        const float var = pq * (1.f/128.f) - mu*mu;
        const float rs  = rsqrtf(var + 1e-5f);
        float2 o2;
        o2.x = (x0 - mu)*rs*gm0 + bt0;
        o2.y = (x1 - mu)*rs*gm1 + bt1;
        *(float2*)(out + g) = o2;
    }
}

extern "C" void kernel_launch(void* const* d_in, const int* in_sizes, int n_in,
                              void* d_out, int out_size, void* d_ws, size_t ws_size,
                              hipStream_t stream)
{
    const float* h     = (const float*)d_in[0];
    const float* Wm1   = (const float*)d_in[1];
    const float* bm1   = (const float*)d_in[2];
    const float* Wm2   = (const float*)d_in[3];
    const float* bm2   = (const float*)d_in[4];
    const float* Wa1   = (const float*)d_in[5];
    const float* ba1   = (const float*)d_in[6];
    const float* wa2   = (const float*)d_in[7];
    // d_in[8] = ba2: constant shift, cancels in softmax
    const float* gamma = (const float*)d_in[9];
    const float* beta  = (const float*)d_in[10];

    float* t_ws   = (float*)d_ws;                 // 4 x 3 MB scratch
    float* msg_ws = t_ws   + ROWS*Dc;
    float* hip_ws = msg_ws + ROWS*Dc;
    float* hjp_ws = hip_ws + ROWS*Dc;
    float* outp   = (float*)d_out;

    hipLaunchKernelGGL(k_gemm_t,    dim3(NRT),    dim3(256), 0, stream,
                       h, Wm1, bm1, t_ws);
    hipLaunchKernelGGL(k_gemm_rest, dim3(NRT*3),  dim3(256), 0, stream,
                       h, t_ws, Wm2, bm2, Wa1, ba1, msg_ws, hip_ws, hjp_ws);
    hipLaunchKernelGGL(k_attn,      dim3(Bc*Kc*2), dim3(512), 0, stream,
                       h, hip_ws, hjp_ws, msg_ws, wa2, gamma, beta, outp);
}

// Round 3
// 102.369 us; speedup vs baseline: 1.0566x; 1.0566x over previous
//
#include <hip/hip_runtime.h>
#include <math.h>

#define Bc 4
#define Lc 48
#define Kc 32
#define Dc 128
#define ROWS (Bc*Lc*Kc)      // 6144
#define RT 48                // rows per GEMM tile
#define NRT (ROWS/RT)        // 128 row tiles per role
#define GT 512               // GEMM kernel threads

static_assert(NRT == 128, "role decode assumes 128 row tiles");

// ---------- register-tile GEMM core: acc[3][4] += sA(rows rg*3..+2) @ sB ----------
__device__ __forceinline__ void gemm_regs(
    const float* __restrict__ sA, const float* __restrict__ sB,
    int rg, int c0, float acc[3][4])
{
    const float* A0 = sA + rg*3*Dc;
    #pragma unroll 8
    for (int k = 0; k < Dc; k += 4) {
        float4 a0 = *(const float4*)(A0 + k);
        float4 a1 = *(const float4*)(A0 + Dc + k);
        float4 a2 = *(const float4*)(A0 + 2*Dc + k);
        float4 b0 = *(const float4*)(sB + (k+0)*Dc + c0);
        float4 b1 = *(const float4*)(sB + (k+1)*Dc + c0);
        float4 b2 = *(const float4*)(sB + (k+2)*Dc + c0);
        float4 b3 = *(const float4*)(sB + (k+3)*Dc + c0);
        float a_[3][4] = {{a0.x,a0.y,a0.z,a0.w},{a1.x,a1.y,a1.z,a1.w},{a2.x,a2.y,a2.z,a2.w}};
        float b_[4][4] = {{b0.x,b0.y,b0.z,b0.w},{b1.x,b1.y,b1.z,b1.w},
                          {b2.x,b2.y,b2.z,b2.w},{b3.x,b3.y,b3.z,b3.w}};
        #pragma unroll
        for (int r = 0; r < 3; ++r)
            #pragma unroll
            for (int c = 0; c < 4; ++c)
                #pragma unroll
                for (int q = 0; q < 4; ++q)
                    acc[r][c] = fmaf(a_[r][q], b_[q][c], acc[r][c]);
    }
}

// ---------- one kernel for all four row-GEMMs ----------
// blocks 0..127   : t = relu(h@Wm1+bm1) (in-LDS) -> msg = t@Wm2+bm2
// blocks 128..255 : hip = h@Wa1[:D] + ba1   (ba1 folded here; ba2 dropped: softmax-invariant)
// blocks 256..383 : hjp = h@Wa1[D:]
__global__ __launch_bounds__(GT) void k_gemm_all(
    const float* __restrict__ h,
    const float* __restrict__ Wm1, const float* __restrict__ bm1,
    const float* __restrict__ Wm2, const float* __restrict__ bm2,
    const float* __restrict__ Wa1, const float* __restrict__ ba1,
    float* __restrict__ msg_ws, float* __restrict__ hip_ws,
    float* __restrict__ hjp_ws)
{
    __shared__ float sA[RT*Dc];      // 24 KB
    __shared__ float sT[RT*Dc];      // 24 KB (role 0 only)
    __shared__ float sB[Dc*Dc];      // 64 KB
    __shared__ float sBias[Dc];

    const int tid = threadIdx.x;
    const int sel = blockIdx.x >> 7;
    const int r0  = (blockIdx.x & 127) * RT;

    const float* W1; const float* b1;
    if (sel == 0)      { W1 = Wm1;          b1 = bm1; }
    else if (sel == 1) { W1 = Wa1;          b1 = ba1; }
    else               { W1 = Wa1 + Dc*Dc;  b1 = nullptr; }

    {   // stage W1 (4096 float4), A rows (1536 float4), bias
        const float4* src = (const float4*)W1;
        float4* dst = (float4*)sB;
        #pragma unroll
        for (int i = 0; i < (Dc*Dc/4)/GT; ++i) dst[tid + i*GT] = src[tid + i*GT];
        const float4* asrc = (const float4*)(h + r0*Dc);
        float4* adst = (float4*)sA;
        #pragma unroll
        for (int i = 0; i < (RT*Dc/4)/GT; ++i) adst[tid + i*GT] = asrc[tid + i*GT];
        if (tid < Dc/4)
            ((float4*)sBias)[tid] = b1 ? ((const float4*)b1)[tid]
                                       : make_float4(0.f, 0.f, 0.f, 0.f);
    }
    __syncthreads();

    const int rg = tid >> 5;             // 0..15 -> rows rg*3..rg*3+2
    const int c0 = (tid & 31) * 4;
    float acc[3][4] = {};
    gemm_regs(sA, sB, rg, c0, acc);

    if (sel != 0) {
        float* out = (sel == 1) ? hip_ws : hjp_ws;
        #pragma unroll
        for (int r = 0; r < 3; ++r) {
            float4 v;
            v.x = acc[r][0] + sBias[c0+0];
            v.y = acc[r][1] + sBias[c0+1];
            v.z = acc[r][2] + sBias[c0+2];
            v.w = acc[r][3] + sBias[c0+3];
            *(float4*)(out + (r0 + rg*3 + r)*Dc + c0) = v;
        }
        return;
    }

    // role 0: t = relu(acc + bm1) staged to sT
    #pragma unroll
    for (int r = 0; r < 3; ++r) {
        float4 v;
        v.x = fmaxf(acc[r][0] + sBias[c0+0], 0.f);
        v.y = fmaxf(acc[r][1] + sBias[c0+1], 0.f);
        v.z = fmaxf(acc[r][2] + sBias[c0+2], 0.f);
        v.w = fmaxf(acc[r][3] + sBias[c0+3], 0.f);
        *(float4*)(sT + (rg*3+r)*Dc + c0) = v;
    }
    __syncthreads();   // all sB(Wm1) reads done + sT visible

    {   // restage Wm2, bm2
        const float4* src = (const float4*)Wm2;
        float4* dst = (float4*)sB;
        #pragma unroll
        for (int i = 0; i < (Dc*Dc/4)/GT; ++i) dst[tid + i*GT] = src[tid + i*GT];
        if (tid < Dc/4) ((float4*)sBias)[tid] = ((const float4*)bm2)[tid];
    }
    __syncthreads();

    float acc2[3][4] = {};
    gemm_regs(sT, sB, rg, c0, acc2);
    #pragma unroll
    for (int r = 0; r < 3; ++r) {
        float4 v;
        v.x = acc2[r][0] + sBias[c0+0];
        v.y = acc2[r][1] + sBias[c0+1];
        v.z = acc2[r][2] + sBias[c0+2];
        v.w = acc2[r][3] + sBias[c0+3];
        *(float4*)(msg_ws + (r0 + rg*3 + r)*Dc + c0) = v;
    }
}

// ---------- logits + softmax + aggregation + residual + LN ----------
// block = (b, k, i-half of 24 i's); 512 threads = 8 waves; wave owns 3 i's.
__global__ __launch_bounds__(512) void k_attn(
    const float* __restrict__ h,
    const float* __restrict__ hip_ws, const float* __restrict__ hjp_ws,
    const float* __restrict__ msg_ws,
    const float* __restrict__ wa2, const float* __restrict__ gamma,
    const float* __restrict__ beta, float* __restrict__ out)
{
    const int blk = blockIdx.x;
    const int b  = blk >> 6;
    const int k  = (blk >> 1) & 31;
    const int i0 = (blk & 1) * 24;

    __shared__ float HJ[48*132];
    __shared__ float MS[48*132];
    __shared__ float HI[24*132];
    __shared__ float WA[Dc];
    __shared__ float GM[Dc];
    __shared__ float BT[Dc];
    __shared__ float WT[24*48];

    const int tid = threadIdx.x;

    for (int idx = tid; idx < 48*32; idx += 512) {
        const int j = idx >> 5, c4 = (idx & 31) * 4;
        const int g = ((b*Lc + j)*Kc + k)*Dc + c4;
        *(float4*)(HJ + j*132 + c4) = *(const float4*)(hjp_ws + g);
        *(float4*)(MS + j*132 + c4) = *(const float4*)(msg_ws + g);
    }
    for (int idx = tid; idx < 24*32; idx += 512) {
        const int i = idx >> 5, c4 = (idx & 31) * 4;
        const int g = ((b*Lc + i0 + i)*Kc + k)*Dc + c4;
        *(float4*)(HI + i*132 + c4) = *(const float4*)(hip_ws + g);
    }
    if (tid < 32)       ((float4*)WA)[tid]      = ((const float4*)wa2)[tid];
    else if (tid < 64)  ((float4*)GM)[tid - 32] = ((const float4*)gamma)[tid - 32];
    else if (tid < 96)  ((float4*)BT)[tid - 64] = ((const float4*)beta)[tid - 64];
    __syncthreads();

    const int wave = tid >> 6;
    const int lane = tid & 63;
    const int il0  = wave * 3;
    const bool jv  = lane < 48;
    const int  jl  = jv ? lane : 0;

    float s0 = 0.f, s1 = 0.f, s2 = 0.f;
    {
        const float* hj = HJ + jl*132;
        const float* hA = HI + il0*132;
        const float* hB = hA + 132;
        const float* hC = hB + 132;
        #pragma unroll 4
        for (int d = 0; d < Dc; d += 4) {
            const float4 hj4 = *(const float4*)(hj + d);
            const float4 w4  = *(const float4*)(WA + d);
            const float4 a4  = *(const float4*)(hA + d);
            const float4 b4  = *(const float4*)(hB + d);
            const float4 c4  = *(const float4*)(hC + d);
            s0 = fmaf(fmaxf(a4.x + hj4.x, 0.f), w4.x, s0);
            s0 = fmaf(fmaxf(a4.y + hj4.y, 0.f), w4.y, s0);
            s0 = fmaf(fmaxf(a4.z + hj4.z, 0.f), w4.z, s0);
            s0 = fmaf(fmaxf(a4.w + hj4.w, 0.f), w4.w, s0);
            s1 = fmaf(fmaxf(b4.x + hj4.x, 0.f), w4.x, s1);
            s1 = fmaf(fmaxf(b4.y + hj4.y, 0.f), w4.y, s1);
            s1 = fmaf(fmaxf(b4.z + hj4.z, 0.f), w4.z, s1);
            s1 = fmaf(fmaxf(b4.w + hj4.w, 0.f), w4.w, s1);
            s2 = fmaf(fmaxf(c4.x + hj4.x, 0.f), w4.x, s2);
            s2 = fmaf(fmaxf(c4.y + hj4.y, 0.f), w4.y, s2);
            s2 = fmaf(fmaxf(c4.z + hj4.z, 0.f), w4.z, s2);
            s2 = fmaf(fmaxf(c4.w + hj4.w, 0.f), w4.w, s2);
        }
    }

    float sv[3] = { jv ? s0 : -1e30f, jv ? s1 : -1e30f, jv ? s2 : -1e30f };
    #pragma unroll
    for (int q = 0; q < 3; ++q) {
        float m = sv[q];
        #pragma unroll
        for (int off = 32; off; off >>= 1) m = fmaxf(m, __shfl_xor(m, off));
        const float p = jv ? __expf(sv[q] - m) : 0.f;
        float sum = p;
        #pragma unroll
        for (int off = 32; off; off >>= 1) sum += __shfl_xor(sum, off);
        if (jv) WT[(il0 + q)*48 + lane] = p / sum;
    }
    __syncthreads();

    const int d0 = lane * 2;
    float ac[3][2] = {};
    const float* wt0 = WT + il0*48;
    const float* wt1 = wt0 + 48;
    const float* wt2 = wt1 + 48;
    #pragma unroll 4
    for (int j = 0; j < 48; ++j) {
        const float2 m2 = *(const float2*)(MS + j*132 + d0);
        const float wA = wt0[j], wB = wt1[j], wC = wt2[j];
        ac[0][0] = fmaf(wA, m2.x, ac[0][0]); ac[0][1] = fmaf(wA, m2.y, ac[0][1]);
        ac[1][0] = fmaf(wB, m2.x, ac[1][0]); ac[1][1] = fmaf(wB, m2.y, ac[1][1]);
        ac[2][0] = fmaf(wC, m2.x, ac[2][0]); ac[2][1] = fmaf(wC, m2.y, ac[2][1]);
    }
    const float gm0 = GM[d0], gm1 = GM[d0+1], bt0 = BT[d0], bt1 = BT[d0+1];
    #pragma unroll
    for (int q = 0; q < 3; ++q) {
        const int i = i0 + il0 + q;
        const int g = ((b*Lc + i)*Kc + k)*Dc + d0;
        const float2 h2 = *(const float2*)(h + g);
        const float x0 = h2.x + ac[q][0];
        const float x1 = h2.y + ac[q][1];
        float ps = x0 + x1;
        float pq = x0*x0 + x1*x1;
        #pragma unroll
        for (int off = 32; off; off >>= 1) {
            ps += __shfl_xor(ps, off);
            pq += __shfl_xor(pq, off);
        }
        const float mu  = ps * (1.f/128.f);
        const float var = pq * (1.f/128.f) - mu*mu;
        const float rs  = rsqrtf(var + 1e-5f);
        float2 o2;
        o2.x = (x0 - mu)*rs*gm0 + bt0;
        o2.y = (x1 - mu)*rs*gm1 + bt1;
        *(float2*)(out + g) = o2;
    }
}

extern "C" void kernel_launch(void* const* d_in, const int* in_sizes, int n_in,
                              void* d_out, int out_size, void* d_ws, size_t ws_size,
                              hipStream_t stream)
{
    const float* h     = (const float*)d_in[0];
    const float* Wm1   = (const float*)d_in[1];
    const float* bm1   = (const float*)d_in[2];
    const float* Wm2   = (const float*)d_in[3];
    const float* bm2   = (const float*)d_in[4];
    const float* Wa1   = (const float*)d_in[5];
    const float* ba1   = (const float*)d_in[6];
    const float* wa2   = (const float*)d_in[7];
    // d_in[8] = ba2: softmax-invariant constant, dropped
    const float* gamma = (const float*)d_in[9];
    const float* beta  = (const float*)d_in[10];

    float* msg_ws = (float*)d_ws;
    float* hip_ws = msg_ws + ROWS*Dc;
    float* hjp_ws = hip_ws + ROWS*Dc;
    float* outp   = (float*)d_out;

    hipLaunchKernelGGL(k_gemm_all, dim3(NRT*3),  dim3(GT),  0, stream,
                       h, Wm1, bm1, Wm2, bm2, Wa1, ba1, msg_ws, hip_ws, hjp_ws);
    hipLaunchKernelGGL(k_attn,     dim3(Bc*Kc*2), dim3(512), 0, stream,
                       h, hip_ws, hjp_ws, msg_ws, wa2, gamma, beta, outp);
}